// Round 12
// baseline (171.455 us; speedup 1.0000x reference)
//
#include <hip/hip_runtime.h>

typedef __bf16 bf16x8 __attribute__((ext_vector_type(8)));
typedef __bf16 bf16x4 __attribute__((ext_vector_type(4)));
typedef float  f32x4  __attribute__((ext_vector_type(4)));

#define NTOK 256
#define DIM  128

// LDS layout (72 KiB -> 2 blocks/CU = 144K <= 160K):
//  QS [256 tok][32 d] bf16, row 64B, swizzle: 16B-slot ^= ((t>>1)&3)<<4   : 16384
//  KS same as QS                                                          : 16384
//  VT [32 d][256 pos] bf16, row 512B, swizzle: byte ^= ((d&7)<<4)         : 16384
//     (V in PV-contraction position space; PV B-frag built in-register)
//  WS [96 col][256B]  per-head qkv weight slice, slot-swizzled            : 24576
//     staged via global_load_lds from the pre-permuted qkvS table;
//     linear dst + pre-swizzled source + swizzled read (rule #21)
#define QS_OFF 0
#define KS_OFF 16384
#define VT_OFF 32768
#define WS_OFF 49152
#define SMEM_BYTES 73728

#define LOG2E 1.4426950408889634f

// ---------------- prep kernel (tiny, run once per launch) ----------------
// g in [0,65536):            biasT fragment table (pre-scaled by log2e)
// g1 = g-65536 in [0,49152): qkvS staged-weight image (bf16, permuted+swizzled)
// remaining 16384:           projT (k-permuted to match attn O-store order)
//
// biasT_frag[((h*16+kt)*16+qt)*64+lane][j] =
//     log2e * bias[h][q=qt*16+(lane&15)][k=kt*16+(lane>>4)*4+j]
//
// qkvS per head = 24576 bytes; byte L holds WS image content:
//   i = L>>8 (weight row 0..95), p = (L>>4)&15 (physical 16B slot), b=(L&15)>>1
//   k    = ((p ^ (i&15))<<3) + b
//   colg = (i>>5)*128 + h*32 + (i&31)          // Q cols | K cols | V cols
//   value = qkv_w[k][colg]
// so an attn read of k-slot s at physical slot s^(i&15) yields k = s*8..s*8+7.
__global__ void prep_kernel(const float* __restrict__ bias_table,
                            const float* __restrict__ qkv_w,
                            const float* __restrict__ proj_w,
                            float* __restrict__ biasT,
                            __bf16* __restrict__ qkvS,
                            __bf16* __restrict__ projT)
{
    const int g = blockIdx.x * 256 + threadIdx.x;       // 0..131071
    if (g < 65536) {
        const int lane = g & 63;
        const int tile = g >> 6;                        // ((h*16+kt)*16+qt)
        const int qt = tile & 15, kt = (tile >> 4) & 15, h = tile >> 8;
        const int lr = lane & 15, rg = lane >> 4;
        // idx(q,k) = (rq-rk+15)*31 + (cq-ck+15);  rq=qt, cq=lr, rk=kt, ck=rg*4+j
        const int base = (qt - kt + 15) * 31 + (lr - rg * 4 + 15);
        float4 v;
        v.x = bias_table[(base - 0) * 4 + h] * LOG2E;
        v.y = bias_table[(base - 1) * 4 + h] * LOG2E;
        v.z = bias_table[(base - 2) * 4 + h] * LOG2E;
        v.w = bias_table[(base - 3) * 4 + h] * LOG2E;
        *reinterpret_cast<float4*>(biasT + (size_t)g * 4) = v;
    } else {
        const int g1 = g - 65536;
        if (g1 < 49152) {
            const int h = g1 / 12288, r = g1 - h * 12288;   // r = bf16 elem in head image
            const int i = r >> 7;                           // weight row 0..95
            const int p = (r >> 3) & 15;                    // physical 16B slot
            const int bb = r & 7;
            const int k = ((p ^ (i & 15)) << 3) + bb;
            const int colg = ((i >> 5) << 7) + (h << 5) + (i & 31);
            qkvS[g1] = (__bf16)qkv_w[k * 384 + colg];
        } else {
            const int g2 = g1 - 49152;
            const int k = g2 >> 7, col = g2 & 127;      // k = source proj_w row
            const int h = k >> 5, d = k & 31;
            const int p = ((d & 15) >> 2) * 8 + ((d >> 4) & 1) * 4 + (d & 3);
            projT[col * 128 + h * 32 + p] = (__bf16)proj_w[g2];
        }
    }
}

// ---------------- fused kernel: QKV + attn + proj epilogue ----------------
// R3 shape: 8 waves x 32 token rows, 2 blocks/CU (LDS-capped), lb(512,2).
// Register model (R11 revision): arch + acc total must stay <= 128 for the
// 4-waves/SIMD tier; current arch 64 + acc ~20 leaves ~40 regs headroom.
// R12 delta: attention rb=0/1 FUSED in one kcc loop — K/V/LDS reads halve,
// two independent S->exp->PV chains double intra-wave ILP (latency-bound).

__global__ __launch_bounds__(512, 2) void attn_main(
    const float* __restrict__ x, const float* __restrict__ noise,
    const float* __restrict__ nstr, const float* __restrict__ biasT,
    const __bf16* __restrict__ qkvS, const __bf16* __restrict__ projT,
    const float* __restrict__ proj_b, __bf16* __restrict__ O_ws,
    float* __restrict__ out)
{
    extern __shared__ char smem[];
    const int b = blockIdx.x, tid = threadIdx.x;
    const int wave = tid >> 6, lane = tid & 63;
    const int lr = lane & 15, hi = lane >> 4;
    const int wrow = wave * 32;

    const float ns    = nstr[0];
    const float scale = 0.17677669529663689f * LOG2E;   // 32^-0.5 * log2e, folded into Q

    // async stage of head hh's weight image into WS: linear LDS dst
    // (wave-uniform base; HW adds lane*16), per-lane global src.
    auto stage_w = [&](int hh) {
#pragma unroll
        for (int is = 0; is < 3; ++is) {
            const __bf16* gsrc = qkvS + hh * 12288 + ((is * 8192 + tid * 16) >> 1);
            char* dst = smem + WS_OFF + is * 8192 + wave * 1024;
            __builtin_amdgcn_global_load_lds(
                (const __attribute__((address_space(1))) void*)(size_t)gsrc,
                (__attribute__((address_space(3))) void*)(unsigned)(size_t)dst,
                16, 0, 0);
        }
    };

    // X fragments in regs (noise added, bf16). Lane (lr,hi) holds X[token=
    // wrow+rb*16+lr][k=kc*32+hi*8+e] — valid as BOTH A-frag (row=token) and
    // B-frag (col=token): A/B lane-data layouts coincide.
    bf16x8 Xf[2][4];
#pragma unroll
    for (int rb = 0; rb < 2; ++rb) {
        const int row = wrow + rb * 16 + lr;
        const float nz = noise[(size_t)b * NTOK + row] * ns;
        const float* prow = x + ((size_t)b * NTOK + row) * DIM;
#pragma unroll
        for (int kc = 0; kc < 4; ++kc) {
            const float4 a0 = *reinterpret_cast<const float4*>(prow + kc * 32 + hi * 8);
            const float4 a1 = *reinterpret_cast<const float4*>(prow + kc * 32 + hi * 8 + 4);
            bf16x8 v;
            v[0] = (__bf16)(a0.x + nz); v[1] = (__bf16)(a0.y + nz);
            v[2] = (__bf16)(a0.z + nz); v[3] = (__bf16)(a0.w + nz);
            v[4] = (__bf16)(a1.x + nz); v[5] = (__bf16)(a1.y + nz);
            v[6] = (__bf16)(a1.z + nz); v[7] = (__bf16)(a1.w + nz);
            Xf[rb][kc] = v;
        }
    }

    stage_w(0);   // head 0 weights; drained by the first __syncthreads

#pragma unroll 1
    for (int h = 0; h < 4; ++h) {
        __syncthreads();   // A: staging complete (implicit vmcnt(0) drain);
                           //    QS/KS/VT rewrite safe vs prev head's readers
        // ---- QKV GEMM: wf from WS (ds_read_b128), reused across both rb ----
#pragma unroll
        for (int ct = 0; ct < 6; ++ct) {
            const int sec = ct >> 1;
            const int i = ct * 16 + lr;                 // weight row; i&15 == lr
            bf16x8 wf[4];
#pragma unroll
            for (int kc = 0; kc < 4; ++kc)
                wf[kc] = *reinterpret_cast<const bf16x8*>(
                    smem + WS_OFF + i * 256 + ((((kc << 2) + hi) ^ lr) << 4));
#pragma unroll
            for (int rb = 0; rb < 2; ++rb) {
                f32x4 c = (f32x4){0.f, 0.f, 0.f, 0.f};
                if (sec < 2) {
                    // transposed: D[col][token] = mfma(W-frag, X-frag)
#pragma unroll
                    for (int kc = 0; kc < 4; ++kc)
                        c = __builtin_amdgcn_mfma_f32_16x16x32_bf16(wf[kc], Xf[rb][kc], c, 0, 0, 0);
                    const int t = wrow + rb * 16 + lr;
                    const int tsw = ((t >> 1) & 3) << 4;
                    bf16x4 pk;
                    if (sec == 0) {
#pragma unroll
                        for (int j = 0; j < 4; ++j) pk[j] = (__bf16)(c[j] * scale);
                        *reinterpret_cast<bf16x4*>(smem + QS_OFF + t * 64 +
                            (((ct & 1) * 32 + hi * 8) ^ tsw)) = pk;
                    } else {
#pragma unroll
                        for (int j = 0; j < 4; ++j) pk[j] = (__bf16)c[j];
                        *reinterpret_cast<bf16x4*>(smem + KS_OFF + t * 64 +
                            (((ct & 1) * 32 + hi * 8) ^ tsw)) = pk;
                    }
                } else {
                    // V NON-swapped: D[token][d] = mfma(X-frag, W-frag)
                    // c[j] = V[token = wrow+rb*16+hi*4+j][d = (ct&1)*16+lr]
                    // position-space packed 8B store (chunk=wave, p=hi*8+rb*4+j)
#pragma unroll
                    for (int kc = 0; kc < 4; ++kc)
                        c = __builtin_amdgcn_mfma_f32_16x16x32_bf16(Xf[rb][kc], wf[kc], c, 0, 0, 0);
                    const int d = (ct & 1) * 16 + lr;
                    bf16x4 pk;
#pragma unroll
                    for (int j = 0; j < 4; ++j) pk[j] = (__bf16)c[j];
                    *reinterpret_cast<bf16x4*>(smem + VT_OFF + d * 512 +
                        ((wave * 64 + hi * 16 + rb * 8) ^ ((d & 7) << 4))) = pk;
                }
            }
        }
        __syncthreads();   // B: Q/K/V ready; WS reads done -> safe to restage

        if (h < 3) stage_w(h + 1);   // async prefetch under the attention phase

        // ---- attention: rb=0 (A) and rb=1 (B) fused in one kcc loop ----
        // K/V fragments loaded ONCE per kcc; two independent S->exp2->PV
        // chains give 2x ILP. P stays fully in-register (position-space V).
        {
            const int tqA = wrow + lr;
            const int tqB = wrow + 16 + lr;
            const bf16x8 qfA = *reinterpret_cast<const bf16x8*>(
                smem + QS_OFF + tqA * 64 + ((hi * 16) ^ (((tqA >> 1) & 3) << 4)));
            const bf16x8 qfB = *reinterpret_cast<const bf16x8*>(
                smem + QS_OFF + tqB * 64 + ((hi * 16) ^ (((tqB >> 1) & 3) << 4)));
            const float* bTA = biasT + ((size_t)((h * 16) * 16 + wave * 2) * 64 + lane) * 4;
            const float* bTB = bTA + 256;               // qt+1 row of the frag table

            float lsA = 0.f, lsB = 0.f;
            f32x4 OA0 = (f32x4){0.f, 0.f, 0.f, 0.f};
            f32x4 OA1 = (f32x4){0.f, 0.f, 0.f, 0.f};
            f32x4 OB0 = (f32x4){0.f, 0.f, 0.f, 0.f};
            f32x4 OB1 = (f32x4){0.f, 0.f, 0.f, 0.f};
#pragma unroll 2
            for (int kcc = 0; kcc < 8; ++kcc) {
                const int tk0 = kcc * 32 + lr;
                const int tk1 = tk0 + 16;
                const bf16x8 kf0 = *reinterpret_cast<const bf16x8*>(
                    smem + KS_OFF + tk0 * 64 + ((hi * 16) ^ (((tk0 >> 1) & 3) << 4)));
                const bf16x8 kf1 = *reinterpret_cast<const bf16x8*>(
                    smem + KS_OFF + tk1 * 64 + ((hi * 16) ^ (((tk1 >> 1) & 3) << 4)));
                const f32x4 bA0 = *reinterpret_cast<const f32x4*>(bTA + (kcc * 2 + 0) * 4096);
                const f32x4 bA1 = *reinterpret_cast<const f32x4*>(bTA + (kcc * 2 + 1) * 4096);
                const f32x4 bB0 = *reinterpret_cast<const f32x4*>(bTB + (kcc * 2 + 0) * 4096);
                const f32x4 bB1 = *reinterpret_cast<const f32x4*>(bTB + (kcc * 2 + 1) * 4096);
                // bias rides in as the MFMA C-operand (pre-scaled by log2e)
                const f32x4 sA0 = __builtin_amdgcn_mfma_f32_16x16x32_bf16(kf0, qfA, bA0, 0, 0, 0);
                const f32x4 sA1 = __builtin_amdgcn_mfma_f32_16x16x32_bf16(kf1, qfA, bA1, 0, 0, 0);
                const f32x4 sB0 = __builtin_amdgcn_mfma_f32_16x16x32_bf16(kf0, qfB, bB0, 0, 0, 0);
                const f32x4 sB1 = __builtin_amdgcn_mfma_f32_16x16x32_bf16(kf1, qfB, bB1, 0, 0, 0);
                // s{tt}[j] = log2e*(S+bias)[k = kcc*32+tt*16+hi*4+j][q]
                // PV B-frag position p = hi*8+e <-> k = kcc*32+(e>>2)*16+hi*4+(e&3)
                bf16x8 pfA, pfB;
#pragma unroll
                for (int j = 0; j < 4; ++j) {
                    const float pA0 = __builtin_amdgcn_exp2f(sA0[j]);  // raw v_exp_f32
                    const float pA1 = __builtin_amdgcn_exp2f(sA1[j]);
                    const float pB0 = __builtin_amdgcn_exp2f(sB0[j]);
                    const float pB1 = __builtin_amdgcn_exp2f(sB1[j]);
                    lsA += pA0; lsA += pA1;
                    lsB += pB0; lsB += pB1;
                    pfA[j] = (__bf16)pA0; pfA[j + 4] = (__bf16)pA1;
                    pfB[j] = (__bf16)pB0; pfB[j + 4] = (__bf16)pB1;
                }
                const bf16x8 v0 = *reinterpret_cast<const bf16x8*>(
                    smem + VT_OFF + lr * 512 + ((kcc * 64 + hi * 16) ^ ((lr & 7) << 4)));
                const bf16x8 v1 = *reinterpret_cast<const bf16x8*>(
                    smem + VT_OFF + (16 + lr) * 512 + ((kcc * 64 + hi * 16) ^ ((lr & 7) << 4)));
                OA0 = __builtin_amdgcn_mfma_f32_16x16x32_bf16(v0, pfA, OA0, 0, 0, 0);
                OA1 = __builtin_amdgcn_mfma_f32_16x16x32_bf16(v1, pfA, OA1, 0, 0, 0);
                OB0 = __builtin_amdgcn_mfma_f32_16x16x32_bf16(v0, pfB, OB0, 0, 0, 0);
                OB1 = __builtin_amdgcn_mfma_f32_16x16x32_bf16(v1, pfB, OB1, 0, 0, 0);
            }
            lsA += __shfl_xor(lsA, 16, 64);
            lsA += __shfl_xor(lsA, 32, 64);
            lsB += __shfl_xor(lsB, 16, 64);
            lsB += __shfl_xor(lsB, 32, 64);
            const float rlA = 1.f / lsA;
            const float rlB = 1.f / lsB;

            // pack O^T halves into one bf16x8 -> single 16B store per rb
            // memory position p = hi*8+e holds d = (e<4)? hi*4+e : 16+hi*4+(e-4)
            bf16x8 ovA, ovB;
#pragma unroll
            for (int j = 0; j < 4; ++j) {
                ovA[j]     = (__bf16)(OA0[j] * rlA);
                ovA[j + 4] = (__bf16)(OA1[j] * rlA);
                ovB[j]     = (__bf16)(OB0[j] * rlB);
                ovB[j + 4] = (__bf16)(OB1[j] * rlB);
            }
            const size_t rpA = ((size_t)b * NTOK + tqA) * DIM + h * 32;
            const size_t rpB = ((size_t)b * NTOK + tqB) * DIM + h * 32;
            *reinterpret_cast<bf16x8*>(O_ws + rpA + hi * 8) = ovA;
            *reinterpret_cast<bf16x8*>(O_ws + rpB + hi * 8) = ovB;
        }
    }

    // ---- fused proj epilogue: out[t] = O[t] @ Wp + b ----
    // The wave reads back ITS OWN O rows (all 4 heads) — written above, so
    // L2-hot. Fragment layouts coincide: af[kc=h] == that head's ov on this
    // lane. Drain stores first (same-wave store->load visibility).
    asm volatile("s_waitcnt vmcnt(0)" ::: "memory");
#pragma unroll
    for (int rb = 0; rb < 2; ++rb) {
        const size_t t = (size_t)b * NTOK + wrow + rb * 16 + lr;
        bf16x8 af[4];
#pragma unroll
        for (int kc = 0; kc < 4; ++kc)
            af[kc] = *reinterpret_cast<const bf16x8*>(O_ws + t * DIM + kc * 32 + hi * 8);
#pragma unroll
        for (int ct = 0; ct < 8; ++ct) {
            f32x4 a = (f32x4){0.f, 0.f, 0.f, 0.f};
#pragma unroll
            for (int kc = 0; kc < 4; ++kc) {
                const bf16x8 wpf = *reinterpret_cast<const bf16x8*>(
                    projT + (ct * 16 + lr) * 128 + kc * 32 + hi * 8);
                a = __builtin_amdgcn_mfma_f32_16x16x32_bf16(wpf, af[kc], a, 0, 0, 0);
            }
            const float4 pbv = *reinterpret_cast<const float4*>(proj_b + ct * 16 + hi * 4);
            f32x4 st;
            st[0] = a[0] + pbv.x; st[1] = a[1] + pbv.y;
            st[2] = a[2] + pbv.z; st[3] = a[3] + pbv.w;
            *reinterpret_cast<f32x4*>(out + t * DIM + ct * 16 + hi * 4) = st;
        }
    }
}

// ---------------- launcher ----------------

extern "C" void kernel_launch(void* const* d_in, const int* in_sizes, int n_in,
                              void* d_out, int out_size, void* d_ws, size_t ws_size,
                              hipStream_t stream)
{
    const float* x          = (const float*)d_in[0];
    const float* noise      = (const float*)d_in[1];
    const float* qkv_w      = (const float*)d_in[2];
    const float* proj_w     = (const float*)d_in[3];
    const float* proj_b     = (const float*)d_in[4];
    const float* bias_table = (const float*)d_in[5];
    const float* nstr       = (const float*)d_in[6];
    float* out = (float*)d_out;
    (void)in_sizes; (void)n_in; (void)out_size; (void)ws_size;

    char* ws = (char*)d_ws;
    const size_t OFF_BIAS  = 0;                                   // 1 MiB
    const size_t OFF_QKVS  = (size_t)1 << 20;                     // 96 KiB
    const size_t OFF_PROJT = OFF_QKVS + 49152 * 2;                // 32 KiB
    const size_t OFF_O     = (size_t)2 << 20;                     // 64 MiB

    float*  biasT = (float*)(ws + OFF_BIAS);
    __bf16* qkvS  = (__bf16*)(ws + OFF_QKVS);
    __bf16* projT = (__bf16*)(ws + OFF_PROJT);
    __bf16* O_ws  = (__bf16*)(ws + OFF_O);

    prep_kernel<<<512, 256, 0, stream>>>(bias_table, qkv_w, proj_w, biasT, qkvS, projT);

    hipFuncSetAttribute(reinterpret_cast<const void*>(attn_main),
                        hipFuncAttributeMaxDynamicSharedMemorySize, SMEM_BYTES);
    attn_main<<<1024, 512, SMEM_BYTES, stream>>>(
        x, noise, nstr, biasT, qkvS, projT, proj_b, O_ws, out);
}